// Round 1
// baseline (1021.426 us; speedup 1.0000x reference)
//
#include <hip/hip_runtime.h>

#define T_DIM 2048
#define B_DIM 32
#define H_DIM 1024
#define I_DIM 1024
#define M_DIM (T_DIM * B_DIM)      // 65536
#define K_DIM I_DIM                // 1024
#define N_DIM H_DIM                // 1024
#define YS_ELEMS (M_DIM * H_DIM)   // 67108864
#define BH (B_DIM * H_DIM)         // 32768

typedef unsigned short u16;
typedef __attribute__((ext_vector_type(8))) short bf16x8;   // 8 bf16 = 4 VGPRs
typedef __attribute__((ext_vector_type(16))) float f32x16;  // MFMA 32x32 acc

__device__ __forceinline__ u16 f2bf(float f) {
  union { float f; unsigned u; } c; c.f = f;
  return (u16)((c.u + 0x7fffu + ((c.u >> 16) & 1u)) >> 16);  // RTNE
}
__device__ __forceinline__ float bf2f(u16 s) {
  union { float f; unsigned u; } c; c.u = ((unsigned)s) << 16;
  return c.f;
}

// fp32 -> bf16 hi/lo split (x = hi + lo + O(2^-18))
__global__ __launch_bounds__(256) void split_kernel(
    const float* __restrict__ x, u16* __restrict__ hi, u16* __restrict__ lo, int n4) {
  int i = blockIdx.x * 256 + threadIdx.x;
  if (i >= n4) return;
  float4 v = ((const float4*)x)[i];
  ushort4 h, l;
  h.x = f2bf(v.x); l.x = f2bf(v.x - bf2f(h.x));
  h.y = f2bf(v.y); l.y = f2bf(v.y - bf2f(h.y));
  h.z = f2bf(v.z); l.z = f2bf(v.z - bf2f(h.z));
  h.w = f2bf(v.w); l.w = f2bf(v.w - bf2f(h.w));
  ((ushort4*)hi)[i] = h;
  ((ushort4*)lo)[i] = l;
}

// async global->LDS, 16B/lane; LDS dst = wave-uniform base + lane*16
__device__ __forceinline__ void gload_lds16(const u16* g, u16* l) {
  __builtin_amdgcn_global_load_lds(
      (const __attribute__((address_space(1))) void*)g,
      (__attribute__((address_space(3))) void*)l, 16, 0, 0);
}

// ---------------------------------------------------------------------------
// GEMM v2: C[m,n] = sum_k (Ah+Al)[m,k]*(Bh+Bl)[n,k], 3-term split, fp32 out.
// 256x256 block tile, BK=32, 8 waves (2M x 4N, each 128x64 = 4x2 of 32x32).
// 4 phases per K-tile (m01/m23 x n0/n1), counted vmcnt(4) (never 0 in loop),
// conflict-free XOR-swizzled LDS (swizzle applied on the GLOBAL source side,
// LDS dest stays linear for global_load_lds), setprio around MFMA clusters.
//
// LDS per buffer: A 32KB (256 rows x 128B = [Ah c0..c3 | Al c0..c3] chunks,
// chunk = 8 u16 of k; stored slot = cc ^ (row&7)), B same. 2 buffers = 128KB.
// LDS row order (so each 8KB staging call = data needed by one phase-group):
//   A: global rows [0-63],[128-191],[64-127],[192-255]  (even-64s first)
//   B: global 32-blocks [0,2,4,6,1,3,5,7]               (even-32s first)
// Staging calls 0-3 = A quarters, 4-7 = B quarters (8KB each, 2 gloads worth
// issued as one call by all 8 waves, wave w writes its own 1KB slice).
// Issue order per tile (staging NEXT tile): a:[0,1] b:[4,5] c:[6,7] d:[2,3].
// Consumption: a needs {0,1,4,5}; b needs {6,7}; c needs {2,3}; d nothing.
// => uniform vmcnt(4) at phases a, b, d; every wait targets loads issued
// 3-4 phases earlier; >=4 loads always in flight.
// ---------------------------------------------------------------------------
#define XOFF  ((unsigned)YS_ELEMS)
#define WOFF  (2u * (unsigned)YS_ELEMS)
#define WLOFF (WOFF + (unsigned)(H_DIM * I_DIM))

#define WAITV(N) asm volatile("s_waitcnt vmcnt(" #N ")" ::: "memory")
#define BARX() do { asm volatile("" ::: "memory"); \
                    __builtin_amdgcn_s_barrier(); \
                    asm volatile("" ::: "memory"); } while (0)

#define STAGE(k, NB) gload_lds16(ws0 + gofs[k] + ks, \
    smem + ((NB) << 15) + ((k) < 4 ? 0 : 16384) + (((k) & 3) << 12) + (wave << 9))

#define RD_APAIR(P, AB) { \
  _Pragma("unroll") for (int i2_ = 0; i2_ < 2; ++i2_) { \
    const u16* ap_ = (AB) + aRowOff[2 * (P) + i2_]; \
    _Pragma("unroll") for (int s_ = 0; s_ < 2; ++s_) { \
      aH[i2_][s_] = *(const bf16x8*)(ap_ + soH[s_]); \
      aL[i2_][s_] = *(const bf16x8*)(ap_ + soL[s_]); \
    } } }

#define RD_B(J, BB) { \
  const u16* bp_ = (BB) + bRowOff[J]; \
  _Pragma("unroll") for (int s_ = 0; s_ < 2; ++s_) { \
    bh2[J][s_] = *(const bf16x8*)(bp_ + soH[s_]); \
    bl2[J][s_] = *(const bf16x8*)(bp_ + soL[s_]); \
  } }

// per-element accumulation order identical to v1: s0:(hh,hl,lh), s1:(hh,hl,lh)
#define MFMA_Q(P, J) { \
  __builtin_amdgcn_s_setprio(1); \
  _Pragma("unroll") for (int s_ = 0; s_ < 2; ++s_) \
  _Pragma("unroll") for (int i2_ = 0; i2_ < 2; ++i2_) { \
    acc[2*(P)+i2_][J] = __builtin_amdgcn_mfma_f32_32x32x16_bf16(aH[i2_][s_], bh2[J][s_], acc[2*(P)+i2_][J], 0, 0, 0); \
    acc[2*(P)+i2_][J] = __builtin_amdgcn_mfma_f32_32x32x16_bf16(aH[i2_][s_], bl2[J][s_], acc[2*(P)+i2_][J], 0, 0, 0); \
    acc[2*(P)+i2_][J] = __builtin_amdgcn_mfma_f32_32x32x16_bf16(aL[i2_][s_], bh2[J][s_], acc[2*(P)+i2_][J], 0, 0, 0); \
  } \
  __builtin_amdgcn_s_setprio(0); }

#define DO_TILE_MAIN(AB, BB, NB) { \
  RD_APAIR(0, AB) RD_B(0, BB) \
  STAGE(0, NB); STAGE(1, NB); \
  WAITV(4); BARX(); \
  MFMA_Q(0, 0) BARX(); \
  RD_B(1, BB) \
  STAGE(4, NB); STAGE(5, NB); \
  WAITV(4); BARX(); \
  MFMA_Q(0, 1) BARX(); \
  RD_APAIR(1, AB) \
  STAGE(6, NB); STAGE(7, NB); \
  BARX(); \
  MFMA_Q(1, 0) BARX(); \
  STAGE(2, NB); STAGE(3, NB); \
  WAITV(4); BARX(); \
  MFMA_Q(1, 1) BARX(); \
  ks += 32; }

#define DO_TILE_LAST(AB, BB) { \
  RD_APAIR(0, AB) RD_B(0, BB) \
  WAITV(2); BARX(); \
  MFMA_Q(0, 0) BARX(); \
  RD_B(1, BB) \
  WAITV(0); BARX(); \
  MFMA_Q(0, 1) BARX(); \
  RD_APAIR(1, AB) \
  BARX(); \
  MFMA_Q(1, 0) BARX(); \
  BARX(); \
  MFMA_Q(1, 1) BARX(); }

__global__ __launch_bounds__(512, 2) void gemm_split(
    const u16* __restrict__ ws0, float* __restrict__ C) {
  __shared__ u16 smem[65536];  // 128 KiB: [buf0: A|B][buf1: A|B]

  const int tid = threadIdx.x;
  const int wave = tid >> 6;
  const int lane = tid & 63;
  const int cl = lane & 31;
  const int kh = lane >> 5;  // k-half within 16-k step
  const int sx = lane & 7;   // swizzle xor (== lds_row & 7)

  // bijective XCD swizzle (1024 blocks % 8 == 0); n varies fastest within
  // an XCD chunk so the 4 N-blocks of one M-tile share A in L2.
  const int bid = blockIdx.x;
  const int id = ((bid & 7) << 7) | (bid >> 3);
  const int m0 = (id >> 2) << 8;
  const int n0 = (id & 3) << 8;

  // staging source element-offsets (from ws0), one per call; advance by ks.
  // decode the linear LDS position each lane's 16B lands at -> which
  // (plane, row, chunk) must live there under the swizzled layout.
  unsigned gofs[8];
#pragma unroll
  for (int k = 0; k < 8; ++k) {
    const int p = ((k & 3) << 13) | (wave << 10) | (lane << 4);  // byte in region
    const int rho = p >> 7;           // LDS row 0-255
    const int slot = (p >> 4) & 7;    // 16B slot within 128B row
    const int cc = slot ^ (rho & 7);  // combined chunk: plane*4 + kchunk
    const int pl = cc >> 2;
    const int c = cc & 3;
    int r; unsigned base;
    if (k < 4) {  // A: LDS row groups [0-63],[128-191],[64-127],[192-255]
      const int g = rho >> 6;
      r = m0 + (((g & 1) << 7) | ((g >> 1) << 6) | (rho & 63));
      base = pl ? XOFF : 0u;
    } else {      // B: LDS 32-row blocks in order [0,2,4,6,1,3,5,7]
      const int q = rho >> 5;
      const int blk = ((q & 3) << 1) | (q >> 2);
      r = n0 + ((blk << 5) | (rho & 31));
      base = pl ? WLOFF : WOFF;
    }
    gofs[k] = base + (unsigned)r * 1024u + (unsigned)(c << 3);
  }

  // reader offsets (u16 units within a buffer's A/B region)
  const int wmH = wave >> 2;           // wave row-half (0/1 -> rows +0/+128)
  const int wn = (wave & 3) << 6;      // wave col base (64-wide)
  int aRowOff[4];
#pragma unroll
  for (int i = 0; i < 4; ++i)          // m-tiles 0..3 -> LDS row * 64 u16
    aRowOff[i] = ((((i >> 1) << 7) | (wmH << 6) | ((i & 1) << 5) | cl) << 6);
  int bRowOff[2];
#pragma unroll
  for (int j = 0; j < 2; ++j) {
    const int b = (wn >> 5) + j;       // global 32-block index
    bRowOff[j] = ((((b & 1) << 7) | ((b >> 1) << 5) | cl) << 6);
  }
  int soH[2], soL[2];                  // swizzled slot offsets per (plane, kstep)
#pragma unroll
  for (int s = 0; s < 2; ++s) {
    soH[s] = ((((s << 1) | kh)) ^ sx) << 3;
    soL[s] = (((4 | (s << 1) | kh)) ^ sx) << 3;
  }

  const u16* a0 = smem;
  const u16* b0 = smem + 16384;
  const u16* a1 = smem + 32768;
  const u16* b1 = smem + 49152;

  bf16x8 aH[2][2], aL[2][2], bh2[2][2], bl2[2][2];
  f32x16 acc[4][2] = {};

  int ks = 0;
  // prologue: stage tile 0 in issue order [0,1,4,5,6,7,2,3]
  STAGE(0, 0); STAGE(1, 0); STAGE(4, 0); STAGE(5, 0);
  STAGE(6, 0); STAGE(7, 0); STAGE(2, 0); STAGE(3, 0);
  ks = 32;
  WAITV(4); BARX();  // calls {0,1,4,5} of tile 0 landed

#pragma unroll 1
  for (int it = 0; it < 15; ++it) {
    DO_TILE_MAIN(a0, b0, 1)
    DO_TILE_MAIN(a1, b1, 0)
  }
  DO_TILE_MAIN(a0, b0, 1)  // tile 30, stages tile 31
  DO_TILE_LAST(a1, b1)     // tile 31, no staging

  // C/D layout: col = lane&31, row = (reg&3) + 8*(reg>>2) + 4*(lane>>5)
  const int rh = (lane >> 5) << 2;
#pragma unroll
  for (int i = 0; i < 4; ++i)
#pragma unroll
    for (int j = 0; j < 2; ++j) {
      const int col = n0 + wn + j * 32 + cl;
      const size_t rb = (size_t)(m0 + wmH * 128 + i * 32 + rh);
#pragma unroll
      for (int rr = 0; rr < 16; ++rr)
        C[(rb + (rr & 3) + 8 * (rr >> 2)) * N_DIM + col] = acc[i][j][rr];
    }
}

// in-place sequential scan over T: h = relu(pre + bias + u*h)
// one thread per (b,h) channel; two register buffers, prefetch depth 64
// (UN 32->64: double in-flight bytes toward the vmcnt-63 cap).
__global__ __launch_bounds__(64) void scan_kernel(
    float* __restrict__ yio, float* __restrict__ hlast,
    const float* __restrict__ bih, const float* __restrict__ bhh,
    const float* __restrict__ u) {
  const int j = blockIdx.x * 64 + threadIdx.x;  // 0..BH-1
  const int hc = j & (H_DIM - 1);
  const float uu = u[hc];
  const float bias = bih[hc] + bhh[hc];
  float h = 0.f;
  float* p = yio + j;
  constexpr int UN = 64;
  float bufA[UN], bufB[UN];
#pragma unroll
  for (int i = 0; i < UN; ++i) bufA[i] = p[(size_t)i * BH];
#pragma unroll 1
  for (int t0 = 0; t0 < T_DIM; t0 += 2 * UN) {
#pragma unroll
    for (int i = 0; i < UN; ++i) bufB[i] = p[(size_t)(t0 + UN + i) * BH];
#pragma unroll
    for (int i = 0; i < UN; ++i) {
      float v = bufA[i] + bias + uu * h;
      h = v > 0.f ? v : 0.f;
      p[(size_t)(t0 + i) * BH] = h;
    }
    if (t0 + 2 * UN < T_DIM) {
#pragma unroll
      for (int i = 0; i < UN; ++i) bufA[i] = p[(size_t)(t0 + 2 * UN + i) * BH];
    }
#pragma unroll
    for (int i = 0; i < UN; ++i) {
      float v = bufB[i] + bias + uu * h;
      h = v > 0.f ? v : 0.f;
      p[(size_t)(t0 + UN + i) * BH] = h;
    }
  }
  hlast[j] = h;
}

extern "C" void kernel_launch(void* const* d_in, const int* in_sizes, int n_in,
                              void* d_out, int out_size, void* d_ws, size_t ws_size,
                              hipStream_t stream) {
  const float* x   = (const float*)d_in[0];
  const float* w   = (const float*)d_in[1];
  const float* bih = (const float*)d_in[2];
  const float* bhh = (const float*)d_in[3];
  const float* u   = (const float*)d_in[4];
  float* out = (float*)d_out;

  // workspace layout: x_hi | x_lo | w_hi | w_lo  (~260 MiB)
  u16* xh = (u16*)d_ws;
  u16* xl = xh + (size_t)YS_ELEMS;
  u16* wh = xl + (size_t)YS_ELEMS;
  u16* wl = wh + (size_t)(H_DIM * I_DIM);

  split_kernel<<<YS_ELEMS / 4 / 256, 256, 0, stream>>>(x, xh, xl, YS_ELEMS / 4);
  split_kernel<<<(H_DIM * I_DIM) / 4 / 256, 256, 0, stream>>>(w, wh, wl, (H_DIM * I_DIM) / 4);
  gemm_split<<<1024, 512, 0, stream>>>((const u16*)d_ws, out);
  scan_kernel<<<BH / 64, 64, 0, stream>>>(out, out + (size_t)YS_ELEMS, bih, bhh, u);
}

// Round 2
// 878.939 us; speedup vs baseline: 1.1621x; 1.1621x over previous
//
#include <hip/hip_runtime.h>

#define T_DIM 2048
#define B_DIM 32
#define H_DIM 1024
#define I_DIM 1024
#define M_DIM (T_DIM * B_DIM)      // 65536
#define K_DIM I_DIM                // 1024
#define N_DIM H_DIM                // 1024
#define YS_ELEMS (M_DIM * H_DIM)   // 67108864
#define BH (B_DIM * H_DIM)         // 32768

typedef unsigned short u16;
typedef __attribute__((ext_vector_type(8))) short bf16x8;   // 8 bf16 = 4 VGPRs
typedef __attribute__((ext_vector_type(16))) float f32x16;  // MFMA 32x32 acc

__device__ __forceinline__ u16 f2bf(float f) {
  union { float f; unsigned u; } c; c.f = f;
  return (u16)((c.u + 0x7fffu + ((c.u >> 16) & 1u)) >> 16);  // RTNE
}
__device__ __forceinline__ float bf2f(u16 s) {
  union { float f; unsigned u; } c; c.u = ((unsigned)s) << 16;
  return c.f;
}

// fp32 -> bf16 hi/lo split (used for W only now; x is split in-GEMM)
__global__ __launch_bounds__(256) void split_kernel(
    const float* __restrict__ x, u16* __restrict__ hi, u16* __restrict__ lo, int n4) {
  int i = blockIdx.x * 256 + threadIdx.x;
  if (i >= n4) return;
  float4 v = ((const float4*)x)[i];
  ushort4 h, l;
  h.x = f2bf(v.x); l.x = f2bf(v.x - bf2f(h.x));
  h.y = f2bf(v.y); l.y = f2bf(v.y - bf2f(h.y));
  h.z = f2bf(v.z); l.z = f2bf(v.z - bf2f(h.z));
  h.w = f2bf(v.w); l.w = f2bf(v.w - bf2f(h.w));
  ((ushort4*)hi)[i] = h;
  ((ushort4*)lo)[i] = l;
}

// async global->LDS, 16B/lane; LDS dst = wave-uniform base + lane*16
__device__ __forceinline__ void gload_lds16(const u16* g, u16* l) {
  __builtin_amdgcn_global_load_lds(
      (const __attribute__((address_space(1))) void*)g,
      (__attribute__((address_space(3))) void*)l, 16, 0, 0);
}

#define WAITV0()    asm volatile("s_waitcnt vmcnt(0)" ::: "memory")
#define WAITLGKM0() asm volatile("s_waitcnt lgkmcnt(0)" ::: "memory")
#define BARX() do { asm volatile("" ::: "memory"); \
                    __builtin_amdgcn_s_barrier(); \
                    asm volatile("" ::: "memory"); } while (0)

// ---------------------------------------------------------------------------
// GEMM v3: C[m,n] = sum_k (Ah+Al)[m,k]*(Bh+Bl)[n,k], fp32 out.
// v1 geometry: 128x128 tile, 4 waves (2x2 of 64x64, each 2x2 of 32x32), BK=32,
// 4096 blocks with v1's L2 grouping. New vs v1:
//  - A is read as fp32 from x and hi/lo-split IN REGISTERS (same f2bf bits),
//    prefetched one K-step ahead, staged via swizzled ds_write_b128.
//  - B double-buffered in LDS; staged for k+32 while computing k; raw
//    barriers + counted waits; vmcnt(0) only ever waits on loads issued a
//    full K-step earlier (never drains in-flight prefetch).
//  - LDS rows are 128B = 8 16B-chunks [Ah c0-3 | Al c0-3], chunk slot
//    XOR-swizzled (slot = cc ^ (row&7)): conflict-free ds_read/ds_write
//    (validated numerically in v2). B source pre-swizzled per m173.
//  LDS: A 16KB (single; "double buffer" is the x regs) + B 2x16KB = 48KB
//  -> 3 blocks/CU co-resident (the v1 stall-hiding asset).
// ---------------------------------------------------------------------------
__global__ __launch_bounds__(256, 3) void gemm_fused(
    const float* __restrict__ X, const u16* __restrict__ Wh,
    const u16* __restrict__ Wl, float* __restrict__ C) {
  __shared__ u16 sA[128 * 64];        // 16 KB, swizzled rows of 128B
  __shared__ u16 sB[2][128 * 64];     // 2 x 16 KB

  const int tid = threadIdx.x;
  const int wave = tid >> 6;
  const int lane = tid & 63;
  const int cl = lane & 31;
  const int kh = lane >> 5;
  const int sx = lane & 7;            // == (frag row & 7) since rows ≡ cl mod 8

  // v1 L2 grouping: 16 groups x (32 m-tiles x 8 n-tiles)
  const int bid = blockIdx.x;
  const int grp = bid >> 8;
  const int rr_ = bid & 255;
  const int n0 = (rr_ >> 5) * 128;
  const int m0 = ((grp << 5) + (rr_ & 31)) * 128;

  // ---- B staging: pre-swizzled global source, linear LDS dest ----
  // call q covers LDS bytes [q*4096, q*4096+4096) = rows 32q..32q+31
  const u16* bsrc[4];
#pragma unroll
  for (int q = 0; q < 4; ++q) {
    const int rho = (q << 5) | (tid >> 3);   // LDS row this lane's 16B lands in
    const int slot = tid & 7;                // 16B slot within 128B row
    const int cc = slot ^ (rho & 7);         // chunk: pl*4 + c
    const int pl = cc >> 2;
    const int c = cc & 3;
    bsrc[q] = (pl ? Wl : Wh) + (size_t)(n0 + rho) * K_DIM + (c << 3);
  }

  // ---- A staging: thread owns row ar, k-half aseg (16 floats) ----
  const int ar = tid >> 1;
  const int aseg = tid & 1;
  const float* xsrc = X + (size_t)(m0 + ar) * K_DIM + (aseg << 4);
  int awofs[2][2];  // u16 offset for (plane, cq): chunk c = aseg*2+cq
#pragma unroll
  for (int pl = 0; pl < 2; ++pl)
#pragma unroll
    for (int cq = 0; cq < 2; ++cq) {
      const int cc = (pl << 2) | (aseg << 1) | cq;
      awofs[pl][cq] = (ar << 6) + ((cc ^ (ar & 7)) << 3);
    }

  // ---- reader offsets ----
  const int wm = (wave & 1) << 6;
  const int wn = (wave >> 1) << 6;
  int aRow[2], bRow[2];
#pragma unroll
  for (int i = 0; i < 2; ++i) {
    aRow[i] = (wm + (i << 5) + cl) << 6;   // u16 base of 128B row
    bRow[i] = (wn + (i << 5) + cl) << 6;
  }
  int soH[2], soL[2];  // swizzled chunk offsets: chunk = s*2+kh (H), +4 (L)
#pragma unroll
  for (int s = 0; s < 2; ++s) {
    soH[s] = ((((s << 1) | kh)) ^ sx) << 3;
    soL[s] = (((4 | (s << 1) | kh)) ^ sx) << 3;
  }

  f32x16 acc[2][2] = {};

  // prologue: x(0) -> regs, B(0) -> sB[0]
  float4 xv0 = ((const float4*)xsrc)[0];
  float4 xv1 = ((const float4*)xsrc)[1];
  float4 xv2 = ((const float4*)xsrc)[2];
  float4 xv3 = ((const float4*)xsrc)[3];
#pragma unroll
  for (int q = 0; q < 4; ++q)
    gload_lds16(bsrc[q], &sB[0][(q << 11) + (wave << 9)]);

#pragma unroll 1
  for (int k0 = 0; k0 < K_DIM; k0 += 32) {
    const int buf = (k0 >> 5) & 1;
    BARX();     // all waves done READING sA / sB[buf^1] from previous step
    WAITV0();   // x(k0) regs + B(k0) LDS landed (issued one full step ago)

    // convert + swizzled-write A(k0): 16 floats -> hi/lo bf16x8 chunks
    {
      float xf[16];
      *(float4*)(xf + 0) = xv0;  *(float4*)(xf + 4) = xv1;
      *(float4*)(xf + 8) = xv2;  *(float4*)(xf + 12) = xv3;
      u16 hh[16], ll[16];
#pragma unroll
      for (int e = 0; e < 16; ++e) {
        hh[e] = f2bf(xf[e]);
        ll[e] = f2bf(xf[e] - bf2f(hh[e]));
      }
#pragma unroll
      for (int cq = 0; cq < 2; ++cq) {
        bf16x8 hv, lv;
#pragma unroll
        for (int e = 0; e < 8; ++e) {
          hv[e] = (short)hh[cq * 8 + e];
          lv[e] = (short)ll[cq * 8 + e];
        }
        *(bf16x8*)(sA + awofs[0][cq]) = hv;
        *(bf16x8*)(sA + awofs[1][cq]) = lv;
      }
    }

    // issue NEXT step's prefetch (stays in flight across the MFMA phase)
    if (k0 + 32 < K_DIM) {
      const float* xs = xsrc + k0 + 32;
      xv0 = ((const float4*)xs)[0];
      xv1 = ((const float4*)xs)[1];
      xv2 = ((const float4*)xs)[2];
      xv3 = ((const float4*)xs)[3];
#pragma unroll
      for (int q = 0; q < 4; ++q)
        gload_lds16(bsrc[q] + k0 + 32, &sB[buf ^ 1][(q << 11) + (wave << 9)]);
    }

    WAITLGKM0();  // my A ds_writes retired
    BARX();       // LDS image (A + B[buf]) consistent for all waves

    // ---- compute: per-s fragment reads (v1 accumulation order) ----
    const u16* bb = &sB[buf][0];
#pragma unroll
    for (int s = 0; s < 2; ++s) {
      bf16x8 ah[2], al[2], bh[2], bl[2];
#pragma unroll
      for (int i = 0; i < 2; ++i) {
        ah[i] = *(const bf16x8*)(sA + aRow[i] + soH[s]);
        al[i] = *(const bf16x8*)(sA + aRow[i] + soL[s]);
        bh[i] = *(const bf16x8*)(bb + bRow[i] + soH[s]);
        bl[i] = *(const bf16x8*)(bb + bRow[i] + soL[s]);
      }
      __builtin_amdgcn_s_setprio(1);
#pragma unroll
      for (int i = 0; i < 2; ++i)
#pragma unroll
        for (int j = 0; j < 2; ++j) {
          acc[i][j] = __builtin_amdgcn_mfma_f32_32x32x16_bf16(ah[i], bh[j], acc[i][j], 0, 0, 0);
          acc[i][j] = __builtin_amdgcn_mfma_f32_32x32x16_bf16(ah[i], bl[j], acc[i][j], 0, 0, 0);
          acc[i][j] = __builtin_amdgcn_mfma_f32_32x32x16_bf16(al[i], bh[j], acc[i][j], 0, 0, 0);
        }
      __builtin_amdgcn_s_setprio(0);
    }
  }

  // C/D layout (m74/m101): col = lane&31, row = (reg&3) + 8*(reg>>2) + 4*(lane>>5)
  const int rh = (lane >> 5) * 4;
#pragma unroll
  for (int i = 0; i < 2; ++i)
#pragma unroll
    for (int j = 0; j < 2; ++j) {
      const int col = n0 + wn + j * 32 + cl;
      const size_t rb = (size_t)(m0 + wm + i * 32 + rh);
#pragma unroll
      for (int rr = 0; rr < 16; ++rr)
        C[(rb + (rr & 3) + 8 * (rr >> 2)) * N_DIM + col] = acc[i][j][rr];
    }
}

// in-place sequential scan over T: h = relu(pre + bias + u*h)
// one thread per (b,h) channel; two register buffers, prefetch depth 64.
__global__ __launch_bounds__(64) void scan_kernel(
    float* __restrict__ yio, float* __restrict__ hlast,
    const float* __restrict__ bih, const float* __restrict__ bhh,
    const float* __restrict__ u) {
  const int j = blockIdx.x * 64 + threadIdx.x;  // 0..BH-1
  const int hc = j & (H_DIM - 1);
  const float uu = u[hc];
  const float bias = bih[hc] + bhh[hc];
  float h = 0.f;
  float* p = yio + j;
  constexpr int UN = 64;
  float bufA[UN], bufB[UN];
#pragma unroll
  for (int i = 0; i < UN; ++i) bufA[i] = p[(size_t)i * BH];
#pragma unroll 1
  for (int t0 = 0; t0 < T_DIM; t0 += 2 * UN) {
#pragma unroll
    for (int i = 0; i < UN; ++i) bufB[i] = p[(size_t)(t0 + UN + i) * BH];
#pragma unroll
    for (int i = 0; i < UN; ++i) {
      float v = bufA[i] + bias + uu * h;
      h = v > 0.f ? v : 0.f;
      p[(size_t)(t0 + i) * BH] = h;
    }
    if (t0 + 2 * UN < T_DIM) {
#pragma unroll
      for (int i = 0; i < UN; ++i) bufA[i] = p[(size_t)(t0 + 2 * UN + i) * BH];
    }
#pragma unroll
    for (int i = 0; i < UN; ++i) {
      float v = bufB[i] + bias + uu * h;
      h = v > 0.f ? v : 0.f;
      p[(size_t)(t0 + UN + i) * BH] = h;
    }
  }
  hlast[j] = h;
}

extern "C" void kernel_launch(void* const* d_in, const int* in_sizes, int n_in,
                              void* d_out, int out_size, void* d_ws, size_t ws_size,
                              hipStream_t stream) {
  const float* x   = (const float*)d_in[0];
  const float* w   = (const float*)d_in[1];
  const float* bih = (const float*)d_in[2];
  const float* bhh = (const float*)d_in[3];
  const float* u   = (const float*)d_in[4];
  float* out = (float*)d_out;

  // workspace: w_hi | w_lo only (~4 MiB); x is split in-register in the GEMM
  u16* wh = (u16*)d_ws;
  u16* wl = wh + (size_t)(H_DIM * I_DIM);

  split_kernel<<<(H_DIM * I_DIM) / 4 / 256, 256, 0, stream>>>(w, wh, wl, (H_DIM * I_DIM) / 4);
  gemm_fused<<<4096, 256, 0, stream>>>(x, wh, wl, out);
  scan_kernel<<<BH / 64, 64, 0, stream>>>(out, out + (size_t)YS_ELEMS, bih, bhh, u);
}

// Round 3
// 877.942 us; speedup vs baseline: 1.1634x; 1.0011x over previous
//
#include <hip/hip_runtime.h>

#define T_DIM 2048
#define B_DIM 32
#define H_DIM 1024
#define I_DIM 1024
#define M_DIM (T_DIM * B_DIM)      // 65536
#define K_DIM I_DIM                // 1024
#define N_DIM H_DIM                // 1024
#define YS_ELEMS (M_DIM * H_DIM)   // 67108864
#define BH (B_DIM * H_DIM)         // 32768

typedef unsigned short u16;
typedef __attribute__((ext_vector_type(8))) short bf16x8;   // 8 bf16 = 4 VGPRs
typedef __attribute__((ext_vector_type(16))) float f32x16;  // MFMA 32x32 acc

__device__ __forceinline__ u16 f2bf(float f) {
  union { float f; unsigned u; } c; c.f = f;
  return (u16)((c.u + 0x7fffu + ((c.u >> 16) & 1u)) >> 16);  // RTNE
}
__device__ __forceinline__ float bf2f(u16 s) {
  union { float f; unsigned u; } c; c.u = ((unsigned)s) << 16;
  return c.f;
}

// fp32 -> bf16 hi/lo split (W only; x is split in-register inside the GEMM)
__global__ __launch_bounds__(256) void split_kernel(
    const float* __restrict__ x, u16* __restrict__ hi, u16* __restrict__ lo, int n4) {
  int i = blockIdx.x * 256 + threadIdx.x;
  if (i >= n4) return;
  float4 v = ((const float4*)x)[i];
  ushort4 h, l;
  h.x = f2bf(v.x); l.x = f2bf(v.x - bf2f(h.x));
  h.y = f2bf(v.y); l.y = f2bf(v.y - bf2f(h.y));
  h.z = f2bf(v.z); l.z = f2bf(v.z - bf2f(h.z));
  h.w = f2bf(v.w); l.w = f2bf(v.w - bf2f(h.w));
  ((ushort4*)hi)[i] = h;
  ((ushort4*)lo)[i] = l;
}

// async global->LDS, 16B/lane; LDS dst = wave-uniform base + lane*16
__device__ __forceinline__ void gload_lds16(const u16* g, u16* l) {
  __builtin_amdgcn_global_load_lds(
      (const __attribute__((address_space(1))) void*)g,
      (__attribute__((address_space(3))) void*)l, 16, 0, 0);
}

#define WAITV4()    asm volatile("s_waitcnt vmcnt(4)" ::: "memory")
#define WAITV0()    asm volatile("s_waitcnt vmcnt(0)" ::: "memory")
#define WAITLGKM0() asm volatile("s_waitcnt lgkmcnt(0)" ::: "memory")
#define BARX() do { asm volatile("" ::: "memory"); \
                    __builtin_amdgcn_s_barrier(); \
                    asm volatile("" ::: "memory"); } while (0)

// ---------------------------------------------------------------------------
// GEMM v4: C = (Ah+Al)(Bh+Bl)^T, 3-term, fp32 out. 128x128 tile, 4 waves,
// BK=32, 3 blocks/CU. vs v3: the hi/lo split + all prefetch issue moved UNDER
// the MFMA phase; between barriers only 4 ds_write_b128 + lgkmcnt(0) remain.
// Counted vmcnt(4) at step top (targets B(k) gloads issued a full step ago;
// x prefetch stays in flight). Issue order pinned: B-gloads, sched_barrier(0),
// then x loads (so the oldest-4 outstanding at step top are ALWAYS B(k)).
// Last K-step peeled (vmcnt(0) - nothing younger outstanding there).
// LDS slot map (write-conflict-free, verified): octet o of plane pl in row r
// lives at slot (pl*4 + ((o&1)<<1) + (o>>1)) ^ h(r), h(r)=((r&3)<<1)|((r>>2)&1).
// Each 8-lane ds_write phase hits 8 distinct slots (was 2 in v3); reads keep
// 8 distinct slots per phase. B staged via gload_lds with pre-swizzled source.
// ---------------------------------------------------------------------------
__global__ __launch_bounds__(256, 3) void gemm_fused(
    const float* __restrict__ X, const u16* __restrict__ Wh,
    const u16* __restrict__ Wl, float* __restrict__ C) {
  __shared__ u16 sA[128 * 64];        // 16 KB
  __shared__ u16 sB[2][128 * 64];     // 2 x 16 KB

  const int tid = threadIdx.x;
  const int wave = tid >> 6;
  const int lane = tid & 63;
  const int cl = lane & 31;
  const int kh = lane >> 5;

  // v1 L2 grouping: 16 groups x (32 m-tiles x 8 n-tiles)
  const int bid = blockIdx.x;
  const int grp = bid >> 8;
  const int rr_ = bid & 255;
  const int n0 = (rr_ >> 5) * 128;
  const int m0 = ((grp << 5) + (rr_ & 31)) * 128;

  // ---- B staging: pre-swizzled global source, linear LDS dest ----
  const u16* bsrc[4];
#pragma unroll
  for (int q = 0; q < 4; ++q) {
    const int rho = (q << 5) | (tid >> 3);   // LDS row this lane's 16B lands in
    const int slot = tid & 7;                // 16B slot within 128B row
    const int hr = (((rho & 3) << 1) | ((rho >> 2) & 1));
    const int cc = slot ^ hr;                // pl*4 + swapped octet
    const int pl = cc >> 2;
    const int o = (((cc & 1) << 1) | ((cc >> 1) & 1));  // un-swap
    bsrc[q] = (pl ? Wl : Wh) + (size_t)(n0 + rho) * K_DIM + (o << 3);
  }

  // ---- A staging: thread owns row ar, k-half aseg (16 floats) ----
  const int ar = tid >> 1;
  const int aseg = tid & 1;
  const float* xsrc = X + (size_t)(m0 + ar) * K_DIM + (aseg << 4);
  const int har = (((ar & 3) << 1) | ((ar >> 2) & 1));
  int awofs[2][2];  // (plane, cq): octet o = aseg*2+cq, slot=(pl4+(cq<<1|aseg))^har
#pragma unroll
  for (int pl = 0; pl < 2; ++pl)
#pragma unroll
    for (int cq = 0; cq < 2; ++cq) {
      const int cc = (pl << 2) | (cq << 1) | aseg;
      awofs[pl][cq] = (ar << 6) + ((cc ^ har) << 3);
    }

  // ---- reader offsets ----
  const int wm = (wave & 1) << 6;
  const int wn = (wave >> 1) << 6;
  int aRow[2], bRow[2];
#pragma unroll
  for (int i = 0; i < 2; ++i) {
    aRow[i] = (wm + (i << 5) + cl) << 6;   // u16 base of 128B row
    bRow[i] = (wn + (i << 5) + cl) << 6;
  }
  // octet o = s*2 + kh -> swapped index (kh<<1)|s; row hash from cl
  const int sx2 = (((cl & 3) << 1) | ((cl >> 2) & 1));
  int soH[2], soL[2];
#pragma unroll
  for (int s = 0; s < 2; ++s) {
    soH[s] = ((((kh << 1) | s)) ^ sx2) << 3;
    soL[s] = (((4 | (kh << 1) | s)) ^ sx2) << 3;
  }

  f32x16 acc[2][2] = {};
  float4 xv0, xv1, xv2, xv3;
  bf16x8 hv0, hv1, lv0, lv1;

#define SPLIT_X() do { \
    float xf[16]; \
    *(float4*)(xf + 0) = xv0;  *(float4*)(xf + 4) = xv1; \
    *(float4*)(xf + 8) = xv2;  *(float4*)(xf + 12) = xv3; \
    u16 hh[16], ll[16]; \
    _Pragma("unroll") for (int e = 0; e < 16; ++e) { \
      hh[e] = f2bf(xf[e]); ll[e] = f2bf(xf[e] - bf2f(hh[e])); } \
    _Pragma("unroll") for (int e = 0; e < 8; ++e) { \
      hv0[e] = (short)hh[e];     lv0[e] = (short)ll[e]; \
      hv1[e] = (short)hh[8 + e]; lv1[e] = (short)ll[8 + e]; } \
  } while (0)

#define LOAD_X(K0) do { const float* xs_ = xsrc + (K0); \
    xv0 = ((const float4*)xs_)[0]; xv1 = ((const float4*)xs_)[1]; \
    xv2 = ((const float4*)xs_)[2]; xv3 = ((const float4*)xs_)[3]; } while (0)

#define WRITE_A() do { \
    *(bf16x8*)(sA + awofs[0][0]) = hv0; *(bf16x8*)(sA + awofs[0][1]) = hv1; \
    *(bf16x8*)(sA + awofs[1][0]) = lv0; *(bf16x8*)(sA + awofs[1][1]) = lv1; \
  } while (0)

#define STAGE_B(K0, NB) do { \
    _Pragma("unroll") for (int q = 0; q < 4; ++q) \
      gload_lds16(bsrc[q] + (K0), &sB[NB][(q << 11) + (wave << 9)]); \
  } while (0)

#define COMPUTE(BUF) do { \
    const u16* bb_ = &sB[BUF][0]; \
    _Pragma("unroll") for (int s = 0; s < 2; ++s) { \
      bf16x8 ah[2], al[2], bh[2], bl[2]; \
      _Pragma("unroll") for (int i = 0; i < 2; ++i) { \
        ah[i] = *(const bf16x8*)(sA + aRow[i] + soH[s]); \
        al[i] = *(const bf16x8*)(sA + aRow[i] + soL[s]); \
        bh[i] = *(const bf16x8*)(bb_ + bRow[i] + soH[s]); \
        bl[i] = *(const bf16x8*)(bb_ + bRow[i] + soL[s]); \
      } \
      __builtin_amdgcn_s_setprio(1); \
      _Pragma("unroll") for (int i = 0; i < 2; ++i) \
      _Pragma("unroll") for (int j = 0; j < 2; ++j) { \
        acc[i][j] = __builtin_amdgcn_mfma_f32_32x32x16_bf16(ah[i], bh[j], acc[i][j], 0, 0, 0); \
        acc[i][j] = __builtin_amdgcn_mfma_f32_32x32x16_bf16(ah[i], bl[j], acc[i][j], 0, 0, 0); \
        acc[i][j] = __builtin_amdgcn_mfma_f32_32x32x16_bf16(al[i], bh[j], acc[i][j], 0, 0, 0); \
      } \
      __builtin_amdgcn_s_setprio(0); \
    } \
  } while (0)

  // ---- prologue: B(0) gloads (oldest), x(0) -> split -> hv/lv, x(1) ----
  STAGE_B(0, 0);
  LOAD_X(0);
  SPLIT_X();       // compiler's xv wait drains B(0) too (prologue only) - fine
  LOAD_X(32);

  // ---- main loop: steps 0..30 ----
#pragma unroll 1
  for (int k0 = 0; k0 < K_DIM - 32; k0 += 32) {
    const int buf = (k0 >> 5) & 1;
    BARX();        // all waves done reading sA(k-1) and sB[buf^1]
    WAITV4();      // B(k) landed (oldest 4); x(k+1) prefetch stays in flight
    WRITE_A();     // hv/lv computed during previous step's MFMA phase
    WAITLGKM0();
    BARX();        // sA(k) + sB[buf] consistent for all waves
    STAGE_B(k0 + 32, buf ^ 1);          // B(k+1), issued FIRST
    __builtin_amdgcn_sched_barrier(0);  // pin: nothing crosses (B before x)
    SPLIT_X();                          // x(k+1) -> hv/lv (compiler vmcnt(4))
    if (k0 + 64 < K_DIM) LOAD_X(k0 + 64);  // x(k+2), issued after B(k+1)
    COMPUTE(buf);                       // overlaps split VALU + load latency
  }

  // ---- peeled last step (k=31, buf=1): nothing younger outstanding ----
  BARX();
  WAITV0();        // B(31) landed
  WRITE_A();
  WAITLGKM0();
  BARX();
  COMPUTE(1);

  // C/D layout (m74/m101): col = lane&31, row = (reg&3) + 8*(reg>>2) + 4*(lane>>5)
  const int rh = (lane >> 5) * 4;
#pragma unroll
  for (int i = 0; i < 2; ++i)
#pragma unroll
    for (int j = 0; j < 2; ++j) {
      const int col = n0 + wn + j * 32 + cl;
      const size_t rb = (size_t)(m0 + wm + i * 32 + rh);
#pragma unroll
      for (int rr = 0; rr < 16; ++rr)
        __builtin_nontemporal_store(acc[i][j][rr],
            &C[(rb + (rr & 3) + 8 * (rr >> 2)) * N_DIM + col]);
    }
#undef SPLIT_X
#undef LOAD_X
#undef WRITE_A
#undef STAGE_B
#undef COMPUTE
}

// in-place sequential scan over T: h = relu(pre + bias + u*h)
// one thread per (b,h) channel; double register buffer, depth 64; nt loads
// (use-once stream, dirty in remote XCD L2s) + nt stores.
__global__ __launch_bounds__(64) void scan_kernel(
    float* __restrict__ yio, float* __restrict__ hlast,
    const float* __restrict__ bih, const float* __restrict__ bhh,
    const float* __restrict__ u) {
  const int j = blockIdx.x * 64 + threadIdx.x;  // 0..BH-1
  const int hc = j & (H_DIM - 1);
  const float uu = u[hc];
  const float bias = bih[hc] + bhh[hc];
  float h = 0.f;
  float* p = yio + j;
  constexpr int UN = 64;
  float bufA[UN], bufB[UN];
#pragma unroll
  for (int i = 0; i < UN; ++i) bufA[i] = __builtin_nontemporal_load(&p[(size_t)i * BH]);
#pragma unroll 1
  for (int t0 = 0; t0 < T_DIM; t0 += 2 * UN) {
#pragma unroll
    for (int i = 0; i < UN; ++i)
      bufB[i] = __builtin_nontemporal_load(&p[(size_t)(t0 + UN + i) * BH]);
#pragma unroll
    for (int i = 0; i < UN; ++i) {
      float v = bufA[i] + bias + uu * h;
      h = v > 0.f ? v : 0.f;
      __builtin_nontemporal_store(h, &p[(size_t)(t0 + i) * BH]);
    }
    if (t0 + 2 * UN < T_DIM) {
#pragma unroll
      for (int i = 0; i < UN; ++i)
        bufA[i] = __builtin_nontemporal_load(&p[(size_t)(t0 + 2 * UN + i) * BH]);
    }
#pragma unroll
    for (int i = 0; i < UN; ++i) {
      float v = bufB[i] + bias + uu * h;
      h = v > 0.f ? v : 0.f;
      __builtin_nontemporal_store(h, &p[(size_t)(t0 + UN + i) * BH]);
    }
  }
  hlast[j] = h;
}

extern "C" void kernel_launch(void* const* d_in, const int* in_sizes, int n_in,
                              void* d_out, int out_size, void* d_ws, size_t ws_size,
                              hipStream_t stream) {
  const float* x   = (const float*)d_in[0];
  const float* w   = (const float*)d_in[1];
  const float* bih = (const float*)d_in[2];
  const float* bhh = (const float*)d_in[3];
  const float* u   = (const float*)d_in[4];
  float* out = (float*)d_out;

  // workspace: w_hi | w_lo only (~4 MiB); x split in-register in the GEMM
  u16* wh = (u16*)d_ws;
  u16* wl = wh + (size_t)(H_DIM * I_DIM);

  split_kernel<<<(H_DIM * I_DIM) / 4 / 256, 256, 0, stream>>>(w, wh, wl, (H_DIM * I_DIM) / 4);
  gemm_fused<<<4096, 256, 0, stream>>>(x, wh, wl, out);
  scan_kernel<<<BH / 64, 64, 0, stream>>>(out, out + (size_t)YS_ELEMS, bih, bhh, u);
}